// Round 3
// baseline (92.958 us; speedup 1.0000x reference)
//
#include <hip/hip_runtime.h>
#include <math.h>

#define NC 15

struct Params {
    const float* p1[3];
    const float* p1d[3];
    const float* p2[3];
    const float* p2d[3];
    const float* lb[3];
    double* sums;   // [3 levels][16 batch][16 terms]
};

__device__ __forceinline__ float bce_f(float x, float t) {
    return fmaxf(x, 0.0f) - x * t + log1pf(expf(-fabsf(x)));
}
__device__ __forceinline__ float sig_f(float x) { return 1.0f / (1.0f + expf(-x)); }
__device__ __forceinline__ float focal_f(float x, float t) {
    float d = t - sig_f(x);
    return bce_f(x, t) * d * d;   // alpha=1, gamma=2 -> |d|^2 == d*d
}
__device__ __forceinline__ float sl1_f(float x, float t) {
    float n = fabsf(x - t);
    return n < 1.0f ? 0.5f * n * n : n - 0.5f;
}

__device__ __forceinline__ float giou_f(const float* b, float lx, float ly, float lw, float lh) {
    float b1x0 = b[0] - b[2] * 0.5f, b1y0 = b[1] - b[3] * 0.5f;
    float b1x1 = b[0] + b[2] * 0.5f, b1y1 = b[1] + b[3] * 0.5f;
    float b2x0 = lx - lw * 0.5f, b2y0 = ly - lh * 0.5f;
    float b2x1 = lx + lw * 0.5f, b2y1 = ly + lh * 0.5f;
    float ax0 = fminf(b1x0, b1x1), ay0 = fminf(b1y0, b1y1);
    float ax1 = fmaxf(b1x0, b1x1), ay1 = fmaxf(b1y0, b1y1);
    float cx0 = fminf(b2x0, b2x1), cy0 = fminf(b2y0, b2y1);
    float cx1 = fmaxf(b2x0, b2x1), cy1 = fmaxf(b2y0, b2y1);
    float a1 = (ax1 - ax0) * (ay1 - ay0);
    float a2 = (cx1 - cx0) * (cy1 - cy0);
    float ltx = fmaxf(ax0, cx0), lty = fmaxf(ay0, cy0);
    float rbx = fminf(ax1, cx1), rby = fminf(ay1, cy1);
    float iw = fmaxf(rbx - ltx, 0.0f), ih = fmaxf(rby - lty, 0.0f);
    float inter = iw * ih;
    float uni = a1 + a2 - inter;
    float iou = inter / (uni + 1e-6f);
    float ex0 = fminf(ax0, cx0), ey0 = fminf(ay0, cy0);
    float ex1 = fmaxf(ax1, cx1), ey1 = fmaxf(ay1, cy1);
    float ew = fmaxf(ex1 - ex0, 0.0f), eh = fmaxf(ey1 - ey0, 0.0f);
    float enc = ew * eh;
    return iou - (enc - uni) / (enc + 1e-6f);
}

__global__ __launch_bounds__(256, 3) void loss_all(Params P) {
    __shared__ __align__(16) float sL[7936];   // label 31*256 (31744 B); later reused for p2 (25*256)
    __shared__ __align__(16) float sA[3328];   // p1d 13*256 (13312 B); later reused for p2d
    __shared__ float red[4][16];

    int tid = threadIdx.x;
    int bid = blockIdx.x;
    int lvl, lblk, shift;
    float invStride;
    if (bid >= 1280)      { lvl = 2; lblk = bid - 1280; shift = 10; invStride = 1.0f / 32.0f; }
    else if (bid >= 1024) { lvl = 1; lblk = bid - 1024; shift = 12; invStride = 1.0f / 16.0f; }
    else                  { lvl = 0; lblk = bid;        shift = 14; invStride = 1.0f / 8.0f;  }
    int cell0 = lblk << 8;
    int c = cell0 + tid;
    int batch = c >> shift;   // uniform across block (G*G multiple of 256)

    const float4* gL = (const float4*)(P.lb[lvl]  + (size_t)cell0 * 31);  // 1984 words
    const float4* gA = (const float4*)(P.p1d[lvl] + (size_t)cell0 * 13);  // 832 words
    const float4* gB = (const float4*)(P.p2d[lvl] + (size_t)cell0 * 13);  // 832 words
    const float4* gQ = (const float4*)(P.p2[lvl]  + (size_t)cell0 * 25);  // 1600 words

    // ---------------- single load burst: everything in flight at once ----------------
    float4 tL[8];
#pragma unroll
    for (int k = 0; k < 7; ++k) tL[k] = gL[tid + 256 * k];
    if (tid < 192) tL[7] = gL[1792 + tid];
    float4 tA[4];
#pragma unroll
    for (int k = 0; k < 3; ++k) tA[k] = gA[tid + 256 * k];
    if (tid < 64) tA[3] = gA[768 + tid];
    float4 rB[4];                       // p2d, held in regs until phase 2
#pragma unroll
    for (int k = 0; k < 3; ++k) rB[k] = gB[tid + 256 * k];
    if (tid < 64) rB[3] = gB[768 + tid];
    float4 rQ[7];                       // p2, held in regs until phase 2
#pragma unroll
    for (int k = 0; k < 6; ++k) rQ[k] = gQ[tid + 256 * k];
    if (tid < 64) rQ[6] = gQ[1536 + tid];
    float conf1 = P.p1[lvl][(size_t)c * 10 + 9];

    float4* vL = (float4*)sL;
    float4* vA = (float4*)sA;
#pragma unroll
    for (int k = 0; k < 7; ++k) vL[tid + 256 * k] = tL[k];
    if (tid < 192) vL[1792 + tid] = tL[7];
#pragma unroll
    for (int k = 0; k < 3; ++k) vA[tid + 256 * k] = tA[k];
    if (tid < 64) vA[768 + tid] = tA[3];
    __syncthreads();

    // ---------------- phase 1: label extract + head 1 ----------------
    const float* L = sL + tid * 31;
    float lx = L[0], ly = L[1], lw = L[2], lh = L[3];
    float l1234[4] = {L[4], L[5], L[6], L[7]};
    float la[4] = {L[8], L[9], L[10], L[11]};
    float lr = L[12];
    float flag = L[13];
    float mix = L[14];
    float area = L[15];
    float gh = 0.0f;
    unsigned nzm = 0u;
#pragma unroll
    for (int k = 0; k < NC; ++k) {
        float cv = L[16 + k];
        gh = fmaxf(gh, cv);
        if (cv != 0.0f) nzm |= (1u << k);
    }

    float obj   = (flag == 1.0f) ? 1.0f : 0.0f;
    float noobj = (flag == 0.0f) ? 1.0f : 0.0f;
    float fuzzy = 1.0f - obj - noobj;
    float conf_t = obj * 0.99f + 0.005f;
    float aw = area + ((area == 0.0f) ? 1.0f : 0.0f);
    float bls = 2.0f - lw * lh * (1.0f / (1024.0f * 1024.0f));

    float v[16];
#pragma unroll
    for (int t = 0; t < 16; ++t) v[t] = 0.0f;
    v[15] = obj;   // per-batch obj count

    float pd[13];
#pragma unroll
    for (int k = 0; k < 13; ++k) pd[k] = sA[tid * 13 + k];
    {
        float xiou = giou_f(pd, lx, ly, lw, lh);
        float siou = bls * (1.0f - fminf(fmaxf(xiou, 0.0f), 1.0f));
        float sobb = 0.0f;
#pragma unroll
        for (int k = 0; k < 4; ++k) { float d = pd[4 + k] - la[k]; sobb += d * d; }
        float dr = pd[8] - lr;
        float sarea = dr * dr;
        float off = expf(-(siou + sobb + sarea));
        float g = (gh + off) * 0.5f;
        float bg = noobj + fuzzy * ((g < 0.3f) ? 1.0f : 0.0f) * (1.0f - fuzzy * g);
        float fg = obj * ((g >= 0.3f) ? 1.0f : 0.0f);
        float foc = focal_f(conf1, conf_t);
        float fma_ = fg * mix * aw;
        v[0] = fg * foc * mix * g;
        v[1] = bg * foc * mix;
        v[2] = fma_ * siou;
        v[3] = fma_ * sobb;
        v[4] = fma_ * sarea;
        float sl = 0.0f;
#pragma unroll
        for (int k = 0; k < 4; ++k) sl += sl1_f(pd[9 + k] * invStride, l1234[k] * invStride);
        v[5] = fg * bls * sl * mix * aw;
    }
    __syncthreads();

    // ---------------- phase 2: dump held registers to LDS ----------------
#pragma unroll
    for (int k = 0; k < 3; ++k) vA[tid + 256 * k] = rB[k];
    if (tid < 64) vA[768 + tid] = rB[3];
#pragma unroll
    for (int k = 0; k < 6; ++k) vL[tid + 256 * k] = rQ[k];
    if (tid < 64) vL[1536 + tid] = rQ[6];
    __syncthreads();

    // ---------------- phase 3: head 2 ----------------
#pragma unroll
    for (int k = 0; k < 13; ++k) pd[k] = sA[tid * 13 + k];
    float siou2, sobb2, sarea2, off2, sl2;
    {
        float xiou = giou_f(pd, lx, ly, lw, lh);
        siou2 = bls * (1.0f - fminf(fmaxf(xiou, 0.0f), 1.0f));
        sobb2 = 0.0f;
#pragma unroll
        for (int k = 0; k < 4; ++k) { float d = pd[4 + k] - la[k]; sobb2 += d * d; }
        float dr = pd[8] - lr;
        sarea2 = dr * dr;
        off2 = expf(-(siou2 + sobb2 + sarea2));
        sl2 = 0.0f;
#pragma unroll
        for (int k = 0; k < 4; ++k) sl2 += sl1_f(pd[9 + k] * invStride, l1234[k] * invStride);
    }
    {
        const float* Q = sL + tid * 25;
        float conf2 = Q[9];
        float g = (gh + off2) * 0.5f;
        float bg = noobj + fuzzy * ((g < 0.3f) ? 1.0f : 0.0f) * (1.0f - fuzzy * g);
        float fg = obj * ((g >= 0.3f) ? 1.0f : 0.0f);
        float foc = focal_f(conf2, conf_t);
        v[6] = fg * foc * mix * g;
        v[7] = bg * foc * mix;

        float pos = 0.0f, neg = 0.0f, wsum = 0.0f, clsb = 0.0f;
#pragma unroll
        for (int k = 0; k < NC; ++k) {
            float x = Q[10 + k];
            bool nz = (nzm >> k) & 1u;
            float smn = (nz ? 0.99f : 0.0f) + (0.01f / 15.0f);
            float b0 = bce_f(x, smn);
            clsb += b0;
            if (nz) {
                pos += bce_f(x, smn * off2);
                wsum += sig_f(x);
            } else {
                neg += b0;
            }
        }
        float wgq = (wsum + gh) * 0.5f;
        float oma = obj * mix * aw;
        v[8] = oma * pos;
        v[9] = oma * neg;
        float fmaw = fg * mix * aw * wgq;
        v[10] = fmaw * siou2;
        v[12] = fmaw * sobb2;
        v[13] = fmaw * sarea2;
        v[14] = fg * bls * sl2 * mix * aw * wgq;
        v[11] = fg * clsb * mix * aw;
    }

    // ---------------- block reduction -> per-(level,batch) double atomics ----------------
    int lane = tid & 63;
    int wid = tid >> 6;
#pragma unroll
    for (int t = 0; t < 16; ++t) {
        float x = v[t];
#pragma unroll
        for (int o = 32; o > 0; o >>= 1) x += __shfl_down(x, o);
        if (lane == 0) red[wid][t] = x;
    }
    __syncthreads();
    if (tid < 16) {
        float total = red[0][tid] + red[1][tid] + red[2][tid] + red[3][tid];
        atomicAdd(&P.sums[((size_t)lvl * 16 + batch) * 16 + tid], (double)total);
    }
}

__global__ void finalize_kernel(const double* __restrict__ S, float* __restrict__ out) {
    if (threadIdx.x == 0 && blockIdx.x == 0) {
        double tot[15];
#pragma unroll
        for (int t = 0; t < 15; ++t) tot[t] = 0.0;
        for (int lb = 0; lb < 48; ++lb) {
            const double* s = S + (size_t)lb * 16;
            double invN = 1.0 / fmax(s[15], 1.0);
            for (int t = 0; t < 15; ++t) tot[t] += s[t] * invN;
        }
        const double invB = 1.0 / 16.0;
        double fg  = (tot[0] + tot[6]) * invB;
        double bg  = (tot[1] + tot[7]) * invB;
        double pos = tot[8]  * invB * 28.0;   // *(NC-1)=14, then *2
        double neg = tot[9]  * invB * 2.0;
        double cls = tot[11] * invB;
        double iou = (tot[2] + tot[10]) * invB * 0.5;
        double s_  = (tot[3] + tot[12]) * invB * 0.5;
        double r   = (tot[4] + tot[13]) * invB * 8.0;    // 16 * avg-of-2
        double l   = (tot[5] + tot[14]) * invB * 0.1;    // 0.2 * avg-of-2
        double loss = fg + bg + iou + s_ + r + pos + neg + l;
        out[0] = (float)loss; out[1] = (float)fg; out[2] = (float)bg;
        out[3] = (float)pos;  out[4] = (float)neg; out[5] = (float)iou;
        out[6] = (float)cls;  out[7] = (float)s_;  out[8] = (float)r;
        out[9] = (float)l;
    }
}

extern "C" void kernel_launch(void* const* d_in, const int* in_sizes, int n_in,
                              void* d_out, int out_size, void* d_ws, size_t ws_size,
                              hipStream_t stream) {
    (void)in_sizes; (void)n_in; (void)out_size; (void)ws_size;
    double* sums = (double*)d_ws;   // 3*16*16 doubles = 6144 B
    hipMemsetAsync(d_ws, 0, 3 * 16 * 16 * sizeof(double), stream);

    Params P;
    for (int lvl = 0; lvl < 3; ++lvl) {
        P.p1[lvl]  = (const float*)d_in[lvl * 5 + 0];
        P.p1d[lvl] = (const float*)d_in[lvl * 5 + 1];
        P.p2[lvl]  = (const float*)d_in[lvl * 5 + 2];
        P.p2d[lvl] = (const float*)d_in[lvl * 5 + 3];
        P.lb[lvl]  = (const float*)d_in[lvl * 5 + 4];
    }
    P.sums = sums;

    loss_all<<<dim3(1344), dim3(256), 0, stream>>>(P);
    finalize_kernel<<<dim3(1), dim3(64), 0, stream>>>(sums, (float*)d_out);
}

// Round 4
// 86.681 us; speedup vs baseline: 1.0724x; 1.0724x over previous
//
#include <hip/hip_runtime.h>
#include <math.h>

#define NC 15

struct Params {
    const float* p1[3];
    const float* p1d[3];
    const float* p2[3];
    const float* p2d[3];
    const float* lb[3];
    double* sums;   // [3 levels][16 batch][16 terms]
};

__device__ __forceinline__ float bce_f(float x, float t) {
    return fmaxf(x, 0.0f) - x * t + log1pf(expf(-fabsf(x)));
}
__device__ __forceinline__ float sig_f(float x) { return 1.0f / (1.0f + expf(-x)); }
__device__ __forceinline__ float focal_f(float x, float t) {
    float d = t - sig_f(x);
    return bce_f(x, t) * d * d;   // alpha=1, gamma=2 -> |d|^2 == d*d
}
__device__ __forceinline__ float sl1_f(float x, float t) {
    float n = fabsf(x - t);
    return n < 1.0f ? 0.5f * n * n : n - 0.5f;
}

__device__ __forceinline__ float giou_f(const float* b, float lx, float ly, float lw, float lh) {
    float b1x0 = b[0] - b[2] * 0.5f, b1y0 = b[1] - b[3] * 0.5f;
    float b1x1 = b[0] + b[2] * 0.5f, b1y1 = b[1] + b[3] * 0.5f;
    float b2x0 = lx - lw * 0.5f, b2y0 = ly - lh * 0.5f;
    float b2x1 = lx + lw * 0.5f, b2y1 = ly + lh * 0.5f;
    float ax0 = fminf(b1x0, b1x1), ay0 = fminf(b1y0, b1y1);
    float ax1 = fmaxf(b1x0, b1x1), ay1 = fmaxf(b1y0, b1y1);
    float cx0 = fminf(b2x0, b2x1), cy0 = fminf(b2y0, b2y1);
    float cx1 = fmaxf(b2x0, b2x1), cy1 = fmaxf(b2y0, b2y1);
    float a1 = (ax1 - ax0) * (ay1 - ay0);
    float a2 = (cx1 - cx0) * (cy1 - cy0);
    float ltx = fmaxf(ax0, cx0), lty = fmaxf(ay0, cy0);
    float rbx = fminf(ax1, cx1), rby = fminf(ay1, cy1);
    float iw = fmaxf(rbx - ltx, 0.0f), ih = fmaxf(rby - lty, 0.0f);
    float inter = iw * ih;
    float uni = a1 + a2 - inter;
    float iou = inter / (uni + 1e-6f);
    float ex0 = fminf(ax0, cx0), ey0 = fminf(ay0, cy0);
    float ex1 = fmaxf(ax1, cx1), ey1 = fmaxf(ay1, cy1);
    float ew = fmaxf(ex1 - ex0, 0.0f), eh = fmaxf(ey1 - ey0, 0.0f);
    float enc = ew * eh;
    return iou - (enc - uni) / (enc + 1e-6f);
}

__global__ __launch_bounds__(256, 3) void loss_all(Params P) {
    __shared__ __align__(16) float sL[7936];   // label 31*256; reused for p2 (25*256)
    __shared__ __align__(16) float sA[3328];   // p1d 13*256; reused for p2d
    __shared__ float red[4][16];

    int tid = threadIdx.x;
    int bid = blockIdx.x;
    int lvl, lblk, shift;
    float invStride;
    if (bid >= 1280)      { lvl = 2; lblk = bid - 1280; shift = 10; invStride = 1.0f / 32.0f; }
    else if (bid >= 1024) { lvl = 1; lblk = bid - 1024; shift = 12; invStride = 1.0f / 16.0f; }
    else                  { lvl = 0; lblk = bid;        shift = 14; invStride = 1.0f / 8.0f;  }
    int cell0 = lblk << 8;
    int c = cell0 + tid;
    int batch = c >> shift;   // uniform across block (G*G multiple of 256)

    const float4* gL = (const float4*)(P.lb[lvl]  + (size_t)cell0 * 31);  // 1984 v4
    const float4* gA = (const float4*)(P.p1d[lvl] + (size_t)cell0 * 13);  // 832 v4
    const float4* gB = (const float4*)(P.p2d[lvl] + (size_t)cell0 * 13);  // 832 v4
    const float4* gQ = (const float4*)(P.p2[lvl]  + (size_t)cell0 * 25);  // 1600 v4

    float4* vL = (float4*)sL;
    float4* vA = (float4*)sA;

    // ---- stage 1: label + p1d -> LDS (transient regs die immediately) ----
    {
        float4 tL[8];
#pragma unroll
        for (int k = 0; k < 7; ++k) tL[k] = gL[tid + 256 * k];
        if (tid < 192) tL[7] = gL[1792 + tid];
        float4 tA[4];
#pragma unroll
        for (int k = 0; k < 3; ++k) tA[k] = gA[tid + 256 * k];
        if (tid < 64) tA[3] = gA[768 + tid];
#pragma unroll
        for (int k = 0; k < 7; ++k) vL[tid + 256 * k] = tL[k];
        if (tid < 192) vL[1792 + tid] = tL[7];
#pragma unroll
        for (int k = 0; k < 3; ++k) vA[tid + 256 * k] = tA[k];
        if (tid < 64) vA[768 + tid] = tA[3];
    }
    float conf1 = P.p1[lvl][(size_t)c * 10 + 9];
    __syncthreads();

    // ---- stage 2 prefetch: p2d + p2 -> regs (latency hides under phase-1) ----
    float4 rB[4];
#pragma unroll
    for (int k = 0; k < 3; ++k) rB[k] = gB[tid + 256 * k];
    if (tid < 64) rB[3] = gB[768 + tid];
    float4 rQ[7];
#pragma unroll
    for (int k = 0; k < 6; ++k) rQ[k] = gQ[tid + 256 * k];
    if (tid < 64) rQ[6] = gQ[1536 + tid];

    // ---------------- phase 1: label extract + head 1 ----------------
    const float* L = sL + tid * 31;
    float lx = L[0], ly = L[1], lw = L[2], lh = L[3];
    float l1234[4] = {L[4], L[5], L[6], L[7]};
    float la[4] = {L[8], L[9], L[10], L[11]};
    float lr = L[12];
    float flag = L[13];
    float mix = L[14];
    float area = L[15];
    float gh = 0.0f;
    unsigned nzm = 0u;
#pragma unroll
    for (int k = 0; k < NC; ++k) {
        float cv = L[16 + k];
        gh = fmaxf(gh, cv);
        if (cv != 0.0f) nzm |= (1u << k);
    }

    float obj   = (flag == 1.0f) ? 1.0f : 0.0f;
    float noobj = (flag == 0.0f) ? 1.0f : 0.0f;
    float fuzzy = 1.0f - obj - noobj;
    float conf_t = obj * 0.99f + 0.005f;
    float aw = area + ((area == 0.0f) ? 1.0f : 0.0f);
    float bls = 2.0f - lw * lh * (1.0f / (1024.0f * 1024.0f));

    float v[16];
#pragma unroll
    for (int t = 0; t < 16; ++t) v[t] = 0.0f;
    v[15] = obj;   // per-batch obj count

    float pd[13];
#pragma unroll
    for (int k = 0; k < 13; ++k) pd[k] = sA[tid * 13 + k];
    {
        float xiou = giou_f(pd, lx, ly, lw, lh);
        float siou = bls * (1.0f - fminf(fmaxf(xiou, 0.0f), 1.0f));
        float sobb = 0.0f;
#pragma unroll
        for (int k = 0; k < 4; ++k) { float d = pd[4 + k] - la[k]; sobb += d * d; }
        float dr = pd[8] - lr;
        float sarea = dr * dr;
        float off = expf(-(siou + sobb + sarea));
        float g = (gh + off) * 0.5f;
        float bg = noobj + fuzzy * ((g < 0.3f) ? 1.0f : 0.0f) * (1.0f - fuzzy * g);
        float fg = obj * ((g >= 0.3f) ? 1.0f : 0.0f);
        float foc = focal_f(conf1, conf_t);
        float fma_ = fg * mix * aw;
        v[0] = fg * foc * mix * g;
        v[1] = bg * foc * mix;
        v[2] = fma_ * siou;
        v[3] = fma_ * sobb;
        v[4] = fma_ * sarea;
        float sl = 0.0f;
#pragma unroll
        for (int k = 0; k < 4; ++k) sl += sl1_f(pd[9 + k] * invStride, l1234[k] * invStride);
        v[5] = fg * bls * sl * mix * aw;
    }
    __syncthreads();

    // ---- dump prefetched regs to LDS ----
#pragma unroll
    for (int k = 0; k < 3; ++k) vA[tid + 256 * k] = rB[k];
    if (tid < 64) vA[768 + tid] = rB[3];
#pragma unroll
    for (int k = 0; k < 6; ++k) vL[tid + 256 * k] = rQ[k];
    if (tid < 64) vL[1536 + tid] = rQ[6];
    __syncthreads();

    // ---------------- phase 2: head 2 ----------------
#pragma unroll
    for (int k = 0; k < 13; ++k) pd[k] = sA[tid * 13 + k];
    float siou2, sobb2, sarea2, off2, sl2;
    {
        float xiou = giou_f(pd, lx, ly, lw, lh);
        siou2 = bls * (1.0f - fminf(fmaxf(xiou, 0.0f), 1.0f));
        sobb2 = 0.0f;
#pragma unroll
        for (int k = 0; k < 4; ++k) { float d = pd[4 + k] - la[k]; sobb2 += d * d; }
        float dr = pd[8] - lr;
        sarea2 = dr * dr;
        off2 = expf(-(siou2 + sobb2 + sarea2));
        sl2 = 0.0f;
#pragma unroll
        for (int k = 0; k < 4; ++k) sl2 += sl1_f(pd[9 + k] * invStride, l1234[k] * invStride);
    }
    {
        const float* Q = sL + tid * 25;
        float conf2 = Q[9];
        float g = (gh + off2) * 0.5f;
        float bg = noobj + fuzzy * ((g < 0.3f) ? 1.0f : 0.0f) * (1.0f - fuzzy * g);
        float fg = obj * ((g >= 0.3f) ? 1.0f : 0.0f);
        float foc = focal_f(conf2, conf_t);
        v[6] = fg * foc * mix * g;
        v[7] = bg * foc * mix;

        float pos = 0.0f, neg = 0.0f, wsum = 0.0f, clsb = 0.0f;
#pragma unroll
        for (int k = 0; k < NC; ++k) {
            float x = Q[10 + k];
            bool nz = (nzm >> k) & 1u;
            float smn = (nz ? 0.99f : 0.0f) + (0.01f / 15.0f);
            float b0 = bce_f(x, smn);
            clsb += b0;
            if (nz) {
                pos += bce_f(x, smn * off2);
                wsum += sig_f(x);
            } else {
                neg += b0;
            }
        }
        float wgq = (wsum + gh) * 0.5f;
        float oma = obj * mix * aw;
        v[8] = oma * pos;
        v[9] = oma * neg;
        float fmaw = fg * mix * aw * wgq;
        v[10] = fmaw * siou2;
        v[12] = fmaw * sobb2;
        v[13] = fmaw * sarea2;
        v[14] = fg * bls * sl2 * mix * aw * wgq;
        v[11] = fg * clsb * mix * aw;
    }

    // ---------------- block reduction -> per-(level,batch) double atomics ----------------
    int lane = tid & 63;
    int wid = tid >> 6;
#pragma unroll
    for (int t = 0; t < 16; ++t) {
        float x = v[t];
#pragma unroll
        for (int o = 32; o > 0; o >>= 1) x += __shfl_down(x, o);
        if (lane == 0) red[wid][t] = x;
    }
    __syncthreads();
    if (tid < 16) {
        float total = red[0][tid] + red[1][tid] + red[2][tid] + red[3][tid];
        atomicAdd(&P.sums[((size_t)lvl * 16 + batch) * 16 + tid], (double)total);
    }
}

__global__ void finalize_kernel(const double* __restrict__ S, float* __restrict__ out) {
    if (threadIdx.x == 0 && blockIdx.x == 0) {
        double tot[15];
#pragma unroll
        for (int t = 0; t < 15; ++t) tot[t] = 0.0;
        for (int lb = 0; lb < 48; ++lb) {
            const double* s = S + (size_t)lb * 16;
            double invN = 1.0 / fmax(s[15], 1.0);
            for (int t = 0; t < 15; ++t) tot[t] += s[t] * invN;
        }
        const double invB = 1.0 / 16.0;
        double fg  = (tot[0] + tot[6]) * invB;
        double bg  = (tot[1] + tot[7]) * invB;
        double pos = tot[8]  * invB * 28.0;   // *(NC-1)=14, then *2
        double neg = tot[9]  * invB * 2.0;
        double cls = tot[11] * invB;
        double iou = (tot[2] + tot[10]) * invB * 0.5;
        double s_  = (tot[3] + tot[12]) * invB * 0.5;
        double r   = (tot[4] + tot[13]) * invB * 8.0;    // 16 * avg-of-2
        double l   = (tot[5] + tot[14]) * invB * 0.1;    // 0.2 * avg-of-2
        double loss = fg + bg + iou + s_ + r + pos + neg + l;
        out[0] = (float)loss; out[1] = (float)fg; out[2] = (float)bg;
        out[3] = (float)pos;  out[4] = (float)neg; out[5] = (float)iou;
        out[6] = (float)cls;  out[7] = (float)s_;  out[8] = (float)r;
        out[9] = (float)l;
    }
}

extern "C" void kernel_launch(void* const* d_in, const int* in_sizes, int n_in,
                              void* d_out, int out_size, void* d_ws, size_t ws_size,
                              hipStream_t stream) {
    (void)in_sizes; (void)n_in; (void)out_size; (void)ws_size;
    double* sums = (double*)d_ws;   // 3*16*16 doubles = 6144 B
    hipMemsetAsync(d_ws, 0, 3 * 16 * 16 * sizeof(double), stream);

    Params P;
    for (int lvl = 0; lvl < 3; ++lvl) {
        P.p1[lvl]  = (const float*)d_in[lvl * 5 + 0];
        P.p1d[lvl] = (const float*)d_in[lvl * 5 + 1];
        P.p2[lvl]  = (const float*)d_in[lvl * 5 + 2];
        P.p2d[lvl] = (const float*)d_in[lvl * 5 + 3];
        P.lb[lvl]  = (const float*)d_in[lvl * 5 + 4];
    }
    P.sums = sums;

    loss_all<<<dim3(1344), dim3(256), 0, stream>>>(P);
    finalize_kernel<<<dim3(1), dim3(64), 0, stream>>>(sums, (float*)d_out);
}

// Round 5
// 68.065 us; speedup vs baseline: 1.3657x; 1.2735x over previous
//
#include <hip/hip_runtime.h>
#include <math.h>

#define NC 15

struct Params {
    const float* p1[3];
    const float* p1d[3];
    const float* p2[3];
    const float* p2d[3];
    const float* lb[3];
    float* part;   // [1344][16] per-block partials
};

__device__ __forceinline__ float bce_f(float x, float t) {
    return fmaxf(x, 0.0f) - x * t + log1pf(expf(-fabsf(x)));
}
__device__ __forceinline__ float sig_f(float x) { return 1.0f / (1.0f + expf(-x)); }
__device__ __forceinline__ float focal_f(float x, float t) {
    float d = t - sig_f(x);
    return bce_f(x, t) * d * d;   // alpha=1, gamma=2 -> |d|^2 == d*d
}
__device__ __forceinline__ float sl1_f(float x, float t) {
    float n = fabsf(x - t);
    return n < 1.0f ? 0.5f * n * n : n - 0.5f;
}

__device__ __forceinline__ float giou_f(const float* b, float lx, float ly, float lw, float lh) {
    float b1x0 = b[0] - b[2] * 0.5f, b1y0 = b[1] - b[3] * 0.5f;
    float b1x1 = b[0] + b[2] * 0.5f, b1y1 = b[1] + b[3] * 0.5f;
    float b2x0 = lx - lw * 0.5f, b2y0 = ly - lh * 0.5f;
    float b2x1 = lx + lw * 0.5f, b2y1 = ly + lh * 0.5f;
    float ax0 = fminf(b1x0, b1x1), ay0 = fminf(b1y0, b1y1);
    float ax1 = fmaxf(b1x0, b1x1), ay1 = fmaxf(b1y0, b1y1);
    float cx0 = fminf(b2x0, b2x1), cy0 = fminf(b2y0, b2y1);
    float cx1 = fmaxf(b2x0, b2x1), cy1 = fmaxf(b2y0, b2y1);
    float a1 = (ax1 - ax0) * (ay1 - ay0);
    float a2 = (cx1 - cx0) * (cy1 - cy0);
    float ltx = fmaxf(ax0, cx0), lty = fmaxf(ay0, cy0);
    float rbx = fminf(ax1, cx1), rby = fminf(ay1, cy1);
    float iw = fmaxf(rbx - ltx, 0.0f), ih = fmaxf(rby - lty, 0.0f);
    float inter = iw * ih;
    float uni = a1 + a2 - inter;
    float iou = inter / (uni + 1e-6f);
    float ex0 = fminf(ax0, cx0), ey0 = fminf(ay0, cy0);
    float ex1 = fmaxf(ax1, cx1), ey1 = fmaxf(ay1, cy1);
    float ew = fmaxf(ex1 - ex0, 0.0f), eh = fmaxf(ey1 - ey0, 0.0f);
    float enc = ew * eh;
    return iou - (enc - uni) / (enc + 1e-6f);
}

__global__ __launch_bounds__(256, 3) void loss_all(Params P) {
    __shared__ __align__(16) float sL[7936];   // label 31*256; reused for p2 (25*256)
    __shared__ __align__(16) float sA[3328];   // p1d 13*256; reused for p2d
    __shared__ float red[4][16];

    int tid = threadIdx.x;
    int bid = blockIdx.x;
    int lvl, lblk, shift;
    float invStride;
    if (bid >= 1280)      { lvl = 2; lblk = bid - 1280; shift = 10; invStride = 1.0f / 32.0f; }
    else if (bid >= 1024) { lvl = 1; lblk = bid - 1024; shift = 12; invStride = 1.0f / 16.0f; }
    else                  { lvl = 0; lblk = bid;        shift = 14; invStride = 1.0f / 8.0f;  }
    int cell0 = lblk << 8;
    int c = cell0 + tid;
    int batch = c >> shift;   // uniform across block (G*G multiple of 256)
    (void)batch;

    const float4* gL = (const float4*)(P.lb[lvl]  + (size_t)cell0 * 31);  // 1984 v4
    const float4* gA = (const float4*)(P.p1d[lvl] + (size_t)cell0 * 13);  // 832 v4
    const float4* gB = (const float4*)(P.p2d[lvl] + (size_t)cell0 * 13);  // 832 v4
    const float4* gQ = (const float4*)(P.p2[lvl]  + (size_t)cell0 * 25);  // 1600 v4

    float4* vL = (float4*)sL;
    float4* vA = (float4*)sA;

    int t191 = tid < 191 ? tid : 191;   // clamped tail indices (dup loads, predicated writes)
    int t63  = tid & 63;

    // ---------------- single load burst (named scalars only -> no scratch) ----------------
    float4 tL0 = gL[tid];
    float4 tL1 = gL[tid + 256];
    float4 tL2 = gL[tid + 512];
    float4 tL3 = gL[tid + 768];
    float4 tL4 = gL[tid + 1024];
    float4 tL5 = gL[tid + 1280];
    float4 tL6 = gL[tid + 1536];
    float4 tL7 = gL[1792 + t191];
    float4 tA0 = gA[tid];
    float4 tA1 = gA[tid + 256];
    float4 tA2 = gA[tid + 512];
    float4 tA3 = gA[768 + t63];
    float4 rB0 = gB[tid];
    float4 rB1 = gB[tid + 256];
    float4 rB2 = gB[tid + 512];
    float4 rB3 = gB[768 + t63];
    float4 rQ0 = gQ[tid];
    float4 rQ1 = gQ[tid + 256];
    float4 rQ2 = gQ[tid + 512];
    float4 rQ3 = gQ[tid + 768];
    float4 rQ4 = gQ[tid + 1024];
    float4 rQ5 = gQ[tid + 1280];
    float4 rQ6 = gQ[1536 + t63];
    float conf1 = P.p1[lvl][(size_t)c * 10 + 9];

    // label + p1d -> LDS (transients die here)
    vL[tid]        = tL0;
    vL[tid + 256]  = tL1;
    vL[tid + 512]  = tL2;
    vL[tid + 768]  = tL3;
    vL[tid + 1024] = tL4;
    vL[tid + 1280] = tL5;
    vL[tid + 1536] = tL6;
    if (tid < 192) vL[1792 + tid] = tL7;
    vA[tid]        = tA0;
    vA[tid + 256]  = tA1;
    vA[tid + 512]  = tA2;
    if (tid < 64) vA[768 + tid] = tA3;
    __syncthreads();

    // ---------------- phase 1: label extract + head 1 ----------------
    const float* L = sL + tid * 31;
    float lx = L[0], ly = L[1], lw = L[2], lh = L[3];
    float l1234[4] = {L[4], L[5], L[6], L[7]};
    float la[4] = {L[8], L[9], L[10], L[11]};
    float lr = L[12];
    float flag = L[13];
    float mix = L[14];
    float area = L[15];
    float gh = 0.0f;
    unsigned nzm = 0u;
#pragma unroll
    for (int k = 0; k < NC; ++k) {
        float cv = L[16 + k];
        gh = fmaxf(gh, cv);
        if (cv != 0.0f) nzm |= (1u << k);
    }

    float obj   = (flag == 1.0f) ? 1.0f : 0.0f;
    float noobj = (flag == 0.0f) ? 1.0f : 0.0f;
    float fuzzy = 1.0f - obj - noobj;
    float conf_t = obj * 0.99f + 0.005f;
    float aw = area + ((area == 0.0f) ? 1.0f : 0.0f);
    float bls = 2.0f - lw * lh * (1.0f / (1024.0f * 1024.0f));

    float v[16];
#pragma unroll
    for (int t = 0; t < 16; ++t) v[t] = 0.0f;
    v[15] = obj;   // per-batch obj count

    float pd[13];
#pragma unroll
    for (int k = 0; k < 13; ++k) pd[k] = sA[tid * 13 + k];
    {
        float xiou = giou_f(pd, lx, ly, lw, lh);
        float siou = bls * (1.0f - fminf(fmaxf(xiou, 0.0f), 1.0f));
        float sobb = 0.0f;
#pragma unroll
        for (int k = 0; k < 4; ++k) { float d = pd[4 + k] - la[k]; sobb += d * d; }
        float dr = pd[8] - lr;
        float sarea = dr * dr;
        float off = expf(-(siou + sobb + sarea));
        float g = (gh + off) * 0.5f;
        float bg = noobj + fuzzy * ((g < 0.3f) ? 1.0f : 0.0f) * (1.0f - fuzzy * g);
        float fg = obj * ((g >= 0.3f) ? 1.0f : 0.0f);
        float foc = focal_f(conf1, conf_t);
        float fma_ = fg * mix * aw;
        v[0] = fg * foc * mix * g;
        v[1] = bg * foc * mix;
        v[2] = fma_ * siou;
        v[3] = fma_ * sobb;
        v[4] = fma_ * sarea;
        float sl = 0.0f;
#pragma unroll
        for (int k = 0; k < 4; ++k) sl += sl1_f(pd[9 + k] * invStride, l1234[k] * invStride);
        v[5] = fg * bls * sl * mix * aw;
    }
    __syncthreads();

    // ---- dump held registers to LDS ----
    vA[tid]        = rB0;
    vA[tid + 256]  = rB1;
    vA[tid + 512]  = rB2;
    if (tid < 64) vA[768 + tid] = rB3;
    vL[tid]        = rQ0;
    vL[tid + 256]  = rQ1;
    vL[tid + 512]  = rQ2;
    vL[tid + 768]  = rQ3;
    vL[tid + 1024] = rQ4;
    vL[tid + 1280] = rQ5;
    if (tid < 64) vL[1536 + tid] = rQ6;
    __syncthreads();

    // ---------------- phase 2: head 2 ----------------
#pragma unroll
    for (int k = 0; k < 13; ++k) pd[k] = sA[tid * 13 + k];
    float siou2, sobb2, sarea2, off2, sl2;
    {
        float xiou = giou_f(pd, lx, ly, lw, lh);
        siou2 = bls * (1.0f - fminf(fmaxf(xiou, 0.0f), 1.0f));
        sobb2 = 0.0f;
#pragma unroll
        for (int k = 0; k < 4; ++k) { float d = pd[4 + k] - la[k]; sobb2 += d * d; }
        float dr = pd[8] - lr;
        sarea2 = dr * dr;
        off2 = expf(-(siou2 + sobb2 + sarea2));
        sl2 = 0.0f;
#pragma unroll
        for (int k = 0; k < 4; ++k) sl2 += sl1_f(pd[9 + k] * invStride, l1234[k] * invStride);
    }
    {
        const float* Q = sL + tid * 25;
        float conf2 = Q[9];
        float g = (gh + off2) * 0.5f;
        float bg = noobj + fuzzy * ((g < 0.3f) ? 1.0f : 0.0f) * (1.0f - fuzzy * g);
        float fg = obj * ((g >= 0.3f) ? 1.0f : 0.0f);
        float foc = focal_f(conf2, conf_t);
        v[6] = fg * foc * mix * g;
        v[7] = bg * foc * mix;

        float pos = 0.0f, neg = 0.0f, wsum = 0.0f, clsb = 0.0f;
#pragma unroll
        for (int k = 0; k < NC; ++k) {
            float x = Q[10 + k];
            bool nz = (nzm >> k) & 1u;
            float smn = (nz ? 0.99f : 0.0f) + (0.01f / 15.0f);
            float b0 = bce_f(x, smn);
            clsb += b0;
            if (nz) {
                pos += bce_f(x, smn * off2);
                wsum += sig_f(x);
            } else {
                neg += b0;
            }
        }
        float wgq = (wsum + gh) * 0.5f;
        float oma = obj * mix * aw;
        v[8] = oma * pos;
        v[9] = oma * neg;
        float fmaw = fg * mix * aw * wgq;
        v[10] = fmaw * siou2;
        v[12] = fmaw * sobb2;
        v[13] = fmaw * sarea2;
        v[14] = fg * bls * sl2 * mix * aw * wgq;
        v[11] = fg * clsb * mix * aw;
    }

    // ---------------- block reduction -> per-block float partials ----------------
    int lane = tid & 63;
    int wid = tid >> 6;
#pragma unroll
    for (int t = 0; t < 16; ++t) {
        float x = v[t];
#pragma unroll
        for (int o = 32; o > 0; o >>= 1) x += __shfl_down(x, o);
        if (lane == 0) red[wid][t] = x;
    }
    __syncthreads();
    if (tid < 16) {
        P.part[(size_t)bid * 16 + tid] =
            red[0][tid] + red[1][tid] + red[2][tid] + red[3][tid];
    }
}

// One block: 768 threads sum per-(lvl,batch) groups, thread 0 finishes in f64.
__global__ __launch_bounds__(1024) void finalize_kernel(const float* __restrict__ part,
                                                        float* __restrict__ out) {
    __shared__ float grp[48][16];
    int t = threadIdx.x;
    if (t < 768) {
        int g = t >> 4, j = t & 15;
        int base, n;
        if (g < 16)      { base = g * 64;             n = 64; }
        else if (g < 32) { base = 1024 + (g - 16) * 16; n = 16; }
        else             { base = 1280 + (g - 32) * 4;  n = 4;  }
        float s = 0.0f;
        for (int b2 = 0; b2 < n; ++b2) s += part[(size_t)(base + b2) * 16 + j];
        grp[g][j] = s;
    }
    __syncthreads();
    if (t == 0) {
        double tot[15];
#pragma unroll
        for (int j = 0; j < 15; ++j) tot[j] = 0.0;
        for (int g = 0; g < 48; ++g) {
            double invN = 1.0 / fmax((double)grp[g][15], 1.0);
            for (int j = 0; j < 15; ++j) tot[j] += (double)grp[g][j] * invN;
        }
        const double invB = 1.0 / 16.0;
        double fg  = (tot[0] + tot[6]) * invB;
        double bg  = (tot[1] + tot[7]) * invB;
        double pos = tot[8]  * invB * 28.0;   // *(NC-1)=14, then *2
        double neg = tot[9]  * invB * 2.0;
        double cls = tot[11] * invB;
        double iou = (tot[2] + tot[10]) * invB * 0.5;
        double s_  = (tot[3] + tot[12]) * invB * 0.5;
        double r   = (tot[4] + tot[13]) * invB * 8.0;    // 16 * avg-of-2
        double l   = (tot[5] + tot[14]) * invB * 0.1;    // 0.2 * avg-of-2
        double loss = fg + bg + iou + s_ + r + pos + neg + l;
        out[0] = (float)loss; out[1] = (float)fg; out[2] = (float)bg;
        out[3] = (float)pos;  out[4] = (float)neg; out[5] = (float)iou;
        out[6] = (float)cls;  out[7] = (float)s_;  out[8] = (float)r;
        out[9] = (float)l;
    }
}

extern "C" void kernel_launch(void* const* d_in, const int* in_sizes, int n_in,
                              void* d_out, int out_size, void* d_ws, size_t ws_size,
                              hipStream_t stream) {
    (void)in_sizes; (void)n_in; (void)out_size; (void)ws_size;
    float* part = (float*)d_ws;   // 1344*16 floats, fully overwritten each call

    Params P;
    for (int lvl = 0; lvl < 3; ++lvl) {
        P.p1[lvl]  = (const float*)d_in[lvl * 5 + 0];
        P.p1d[lvl] = (const float*)d_in[lvl * 5 + 1];
        P.p2[lvl]  = (const float*)d_in[lvl * 5 + 2];
        P.p2d[lvl] = (const float*)d_in[lvl * 5 + 3];
        P.lb[lvl]  = (const float*)d_in[lvl * 5 + 4];
    }
    P.part = part;

    loss_all<<<dim3(1344), dim3(256), 0, stream>>>(P);
    finalize_kernel<<<dim3(1), dim3(1024), 0, stream>>>(part, (float*)d_out);
}